// Round 22
// baseline (294.808 us; speedup 1.0000x reference)
//
#include <hip/hip_runtime.h>

typedef float f32x4 __attribute__((ext_vector_type(4)));
typedef unsigned int u32x4 __attribute__((ext_vector_type(4)));
typedef _Float16 f16x8 __attribute__((ext_vector_type(8)));
typedef unsigned short u16;
typedef unsigned int u32;

// ---- constants ----
#define NWIN 8192
#define MAX_LOG_SCALE 4.605170185988091f  // log(100)
#define LOG2E 1.4426950408889634f

// Wave = head end-to-end; 3 barriers; launch_bounds(256,4) (reg-pinned ~128
// unified regs/wave; tighter caps spill — rounds 4/6/10/12).
// Round 22 = R21 + both reductions taken OFF the per-nt serial chain
// (R21 showed VALU 46->29% with flat dur: latency-bound on DS round trips):
//  (1) deferred q-norm: store RAW biased q immediately; ss+pex+rn overlap the
//      q store->read round trip; norm folded into exp arg (esc = sc*rn)
//  (2) deferred softmax div: pex(psum) write+READ still precede the P store
//      (aliasing: pex@+1792 overlaps P rows 14-15 — read-before-overwrite),
//      but rs is computed late and applied at the O store; the P->ap->PV
//      chain never waits on the pex result.
// PLATFORM RULE (R15/R16): __shfl_* across the 32-lane boundary is broken —
// masks 1/2/4/8 only; cross-group sums go through pex (LDS, in-order).
// LDS (40 KB -> 4 blocks/CU):
//   RX1  [0,16K):   x1 f16 [64][128] swz
//   RX2  [16K,32K): x2 f16 [64][128] swz -> O overlay after barrier (2)
//   RBNC [32K,40K): per-wave 2 KB strip (vT s128swz -> k-hat s80 -> q-raw s80
//                   -> P s128swz, sequential wave-local; pex@1792)
#define RX1 0
#define RX2 16384
#define RBNC 32768
#define LDS_BYTES 40960

__device__ __forceinline__ void mfma16(f32x4& acc, u32x4 a, u32x4 b) {
  acc = __builtin_amdgcn_mfma_f32_16x16x32_f16(
      __builtin_bit_cast(f16x8, a), __builtin_bit_cast(f16x8, b), acc, 0, 0, 0);
}

__device__ __forceinline__ u16 f2h(float f) {
  return __builtin_bit_cast(u16, (_Float16)f);
}
__device__ __forceinline__ u32 pkh(float x, float y) {  // packed f32->f16 (RTZ)
  return __builtin_bit_cast(u32, __builtin_amdgcn_cvt_pkrtz(x, y));
}

// XOR swizzle within a row (row stride 256B or 128B); bijective, stays in-row.
__device__ __forceinline__ int swz(int row, int colbyte) {
  return colbyte ^ ((row & 7) << 4);
}
__device__ __forceinline__ u32x4 ldsfrag(const char* p, int row, int colbyte, int stride) {
  return *(const u32x4*)(p + row * stride + swz(row, colbyte));
}
__device__ __forceinline__ void lds_st16(char* p, int row, int colbyte, int stride, u16 v) {
  *(u16*)(p + row * stride + swz(row, colbyte)) = v;
}
__device__ __forceinline__ u32x4 gfrag(const u16* p) {
  return *(const u32x4*)p;
}

// ---------- weight prep: f32 -> f16 (contiguous qw|kvw|pw) + head scales ----------
__global__ void wca_prep(const float* __restrict__ qw, const float* __restrict__ kvw,
                         const float* __restrict__ pw, const float* __restrict__ ls,
                         u16* __restrict__ wh, float* __restrict__ scales) {
  int t = blockIdx.x * 256 + threadIdx.x;   // 0..16383, one float4 each
  int e = t * 4;
  const float* src;
  int off;
  if (e < 16384)      { src = qw;  off = e; }
  else if (e < 49152) { src = kvw; off = e - 16384; }
  else                { src = pw;  off = e - 49152; }
  float4 v = *(const float4*)(src + off);
  uint2 o = { pkh(v.x, v.y), pkh(v.z, v.w) };
  *(uint2*)(wh + e) = o;
  if (t < 4) scales[t] = __expf(fminf(ls[t], MAX_LOG_SCALE)) * LOG2E;
}

// ---------- main kernel: one window per block, wave = head, 3 barriers ----------
__global__ void __launch_bounds__(256, 4) wca_kernel(
    const float* __restrict__ x1, const float* __restrict__ x2,
    const float* __restrict__ qb, const float* __restrict__ vb,
    const float* __restrict__ pb, const u16* __restrict__ wh,
    const float* __restrict__ scales, float* __restrict__ out) {
  __shared__ char smem[LDS_BYTES];
  const int b = blockIdx.x;
  const int tid = threadIdx.x;
  const int wv = tid >> 6;          // wave = head 0..3
  const int lane = tid & 63;
  const int lr = lane & 15;
  const int lg = lane >> 4;
  const int h32 = wv * 32;
  const u16* qw_  = wh;                     // 128x128
  const u16* kvwk = wh + 16384;             // k-part rows 0..127
  const u16* kvwv = wh + 16384 + 16384;     // v-part rows 0..127
  const u16* pw_  = wh + 49152;             // 128x128
  char* bnc = smem + RBNC + wv * 2048;      // wave-private bounce strip
  char* pex = bnc + 1792;                   // 256B partial-sum exchange area

  // ---- phase 0: stage x1 AND x2 -> f16 LDS (all 16 loads hoisted) ----
  {
    const float4* p1 = (const float4*)(x1 + (size_t)b * 8192);
    const float4* p2 = (const float4*)(x2 + (size_t)b * 8192);
    float4 a[8], c[8];
#pragma unroll
    for (int i = 0; i < 8; ++i) { a[i] = p1[i * 256 + tid]; c[i] = p2[i * 256 + tid]; }
#pragma unroll
    for (int i = 0; i < 8; ++i) {
      int e = (i * 256 + tid) * 4;
      int row = e >> 7;
      int colb = (e & 127) * 2;
      uint2 pa = { pkh(a[i].x, a[i].y), pkh(a[i].z, a[i].w) };
      uint2 pc = { pkh(c[i].x, c[i].y), pkh(c[i].z, c[i].w) };
      *(uint2*)(smem + RX1 + row * 256 + swz(row, colb)) = pa;
      *(uint2*)(smem + RX2 + row * 256 + swz(row, colb)) = pc;
    }
  }
  __syncthreads();  // (1) x1,x2 visible

  // ---- V pass: vT(c,m) = sum_k kvw_v[h32+c][k]*x2[m][k] + vb (jt-merged) ----
  u32x4 bv[2][2];
  {
    u32x4 akv[2][4];
#pragma unroll
    for (int jt = 0; jt < 2; ++jt)
#pragma unroll
      for (int kc = 0; kc < 4; ++kc)
        akv[jt][kc] = gfrag(kvwv + (h32 + jt * 16 + lr) * 128 + kc * 32 + lg * 8);
    f32x4 vc[2][4];
#pragma unroll
    for (int jt = 0; jt < 2; ++jt)
#pragma unroll
      for (int nt = 0; nt < 4; ++nt) vc[jt][nt] = (f32x4){0.f, 0.f, 0.f, 0.f};
#pragma unroll
    for (int nt = 0; nt < 4; ++nt) {
      u32x4 bx[4];
#pragma unroll
      for (int kc = 0; kc < 4; ++kc)
        bx[kc] = ldsfrag(smem + RX2, nt * 16 + lr, kc * 64 + lg * 16, 256);
#pragma unroll
      for (int jt = 0; jt < 2; ++jt)
#pragma unroll
        for (int kc = 0; kc < 4; ++kc) mfma16(vc[jt][nt], akv[jt][kc], bx[kc]);
    }
#pragma unroll
    for (int jt = 0; jt < 2; ++jt) {
      float vbias[4];
#pragma unroll
      for (int i = 0; i < 4; ++i) vbias[i] = vb[h32 + jt * 16 + lg * 4 + i];
#pragma unroll
      for (int nt = 0; nt < 4; ++nt)
#pragma unroll
        for (int i = 0; i < 4; ++i)
          lds_st16(bnc, lg * 4 + i, (nt * 16 + lr) * 2, 128,
                   f2h(vc[jt][nt][i] + vbias[i]));
#pragma unroll
      for (int kc = 0; kc < 2; ++kc)
        bv[jt][kc] = ldsfrag(bnc, lr, kc * 64 + lg * 16, 128);  // wave-local RAW
    }
  }

  // ---- K pass (SWAPPED): lane holds k[tok=mt*16+lr][ch lg*4+i | 16+lg*4+i] ----
  u32x4 bk[4];
  {
    u32x4 bkw[2][4];
#pragma unroll
    for (int jt = 0; jt < 2; ++jt)
#pragma unroll
      for (int kc = 0; kc < 4; ++kc)
        bkw[jt][kc] = gfrag(kvwk + (h32 + jt * 16 + lr) * 128 + kc * 32 + lg * 8);
#pragma unroll
    for (int mt = 0; mt < 4; ++mt) {
      f32x4 c0 = {0.f, 0.f, 0.f, 0.f}, c1 = {0.f, 0.f, 0.f, 0.f};
#pragma unroll
      for (int kc = 0; kc < 4; ++kc) {
        u32x4 ax = ldsfrag(smem + RX2, mt * 16 + lr, kc * 64 + lg * 16, 256);
        mfma16(c0, bkw[0][kc], ax);   // A=weights(channels), B=x2(tokens)
        mfma16(c1, bkw[1][kc], ax);
      }
      // lane-local channel sum + pex exchange across lg groups (no 16/32 shfl)
      float ss = 0.f;
#pragma unroll
      for (int i = 0; i < 4; ++i)
        ss = fmaf(c0[i], c0[i], fmaf(c1[i], c1[i], ss));
      *(float*)(pex + lr * 16 + lg * 4) = ss;
      float4 ps = *(const float4*)(pex + lr * 16);
      float rn = 1.0f / fmaxf(sqrtf(ps.x + ps.y + ps.z + ps.w), 1e-12f);
      // packed k-hat store: [tok=lr][ch] stride 80 (proven bank pattern)
      uint2 k0 = { pkh(c0[0] * rn, c0[1] * rn), pkh(c0[2] * rn, c0[3] * rn) };
      uint2 k1 = { pkh(c1[0] * rn, c1[1] * rn), pkh(c1[2] * rn, c1[3] * rn) };
      *(uint2*)(bnc + lr * 80 + lg * 8) = k0;
      *(uint2*)(bnc + lr * 80 + 32 + lg * 8) = k1;
      bk[mt] = *(const u32x4*)(bnc + lr * 80 + lg * 16);  // wave-local RAW
    }
  }
  __syncthreads();  // (2) all waves done reading x2 -> O may overlay RX2

  // ---- Q + attention per nt (deferred q-norm, deferred softmax div) ----
  const float sc = scales[wv];  // includes log2(e)
  float qb0v[4], qb1v[4];       // bias by CHANNEL (lg*4+i) for swapped layout
#pragma unroll
  for (int i = 0; i < 4; ++i) {
    qb0v[i] = qb[h32 + lg * 4 + i];
    qb1v[i] = qb[h32 + 16 + lg * 4 + i];
  }
#pragma unroll
  for (int nt = 0; nt < 4; ++nt) {
    f32x4 q0 = {0.f, 0.f, 0.f, 0.f}, q1 = {0.f, 0.f, 0.f, 0.f};
#pragma unroll
    for (int kc = 0; kc < 4; ++kc) {
      u32x4 a = ldsfrag(smem + RX1, nt * 16 + lr, kc * 64 + lg * 16, 256);
      u32x4 w0 = gfrag(qw_ + (h32 + lr) * 128 + kc * 32 + lg * 8);
      u32x4 w1 = gfrag(qw_ + (h32 + 16 + lr) * 128 + kc * 32 + lg * 8);
      mfma16(q0, w0, a);   // SWAPPED: lane holds q[tok=nt*16+lr][ch lg*4+i]
      mfma16(q1, w1, a);   // channels 16+lg*4+i
    }
    // bias; store RAW q immediately (deferred norm — R11 pattern, pex-safe)
#pragma unroll
    for (int i = 0; i < 4; ++i) { q0[i] += qb0v[i]; q1[i] += qb1v[i]; }
    uint2 g0 = { pkh(q0[0], q0[1]), pkh(q0[2], q0[3]) };
    uint2 g1 = { pkh(q1[0], q1[1]), pkh(q1[2], q1[3]) };
    *(uint2*)(bnc + lr * 80 + lg * 8) = g0;
    *(uint2*)(bnc + lr * 80 + 32 + lg * 8) = g1;
    // ss + pex overlap the q store->read round trip (pex disjoint from q strip;
    // prev nt's ap reads already issued before these writes — aliasing safe)
    float ss = 0.f;
#pragma unroll
    for (int i = 0; i < 4; ++i)
      ss = fmaf(q0[i], q0[i], fmaf(q1[i], q1[i], ss));
    *(float*)(pex + lr * 16 + lg * 4) = ss;
    float4 ps0 = *(const float4*)(pex + lr * 16);
    u32x4 aq = *(const u32x4*)(bnc + lr * 80 + lg * 16);  // raw q, token=lr

    // QK (swapped): p4[mt][i] = rawdot[k = mt*16+lg*4+i][q = lr]
    f32x4 p4[4];
#pragma unroll
    for (int mt = 0; mt < 4; ++mt) {
      f32x4 z = {0.f, 0.f, 0.f, 0.f};
      mfma16(z, bk[mt], aq);
      p4[mt] = z;
    }
    // norm folded into exp arg: esc = sc / ||q||  (k already normalized)
    float esc = sc / fmaxf(sqrtf(ps0.x + ps0.y + ps0.z + ps0.w), 1e-12f);
    float psum = 0.f;
#pragma unroll
    for (int mt = 0; mt < 4; ++mt)
#pragma unroll
      for (int i = 0; i < 4; ++i) {
        float p = exp2f(fmaf(p4[mt][i], esc, -sc));
        p4[mt][i] = p;
        psum += p;
      }
    // pex(psum) write + READ must precede the P store (pex aliases P rows
    // 14-15); rs is COMPUTED late so the P->ap->PV chain never waits on it.
    *(float*)(pex + lr * 16 + lg * 4) = psum;
    float4 ps1 = *(const float4*)(pex + lr * 16);

    // P store UNNORMALIZED -> strip [row=q=lr][col=m], stride 128 swz, 8B packed
#pragma unroll
    for (int mt = 0; mt < 4; ++mt) {
      uint2 pp = { pkh(p4[mt][0], p4[mt][1]), pkh(p4[mt][2], p4[mt][3]) };
      int colb = mt * 32 + lg * 8;
      *(uint2*)(bnc + lr * 128 + swz(lr, colb)) = pp;
    }
    // ap read (row = lr, m = kc*32 + lg*8 + j)
    u32x4 ap[2];
#pragma unroll
    for (int kc = 0; kc < 2; ++kc)
      ap[kc] = ldsfrag(bnc, lr, kc * 64 + lg * 16, 128);  // wave-local RAW
    const float rs = 1.0f / (ps1.x + ps1.y + ps1.z + ps1.w);  // late use of ps1

    // PV SWAPPED: lane holds O[ch = h32+ct*16+lg*4+i][tok = nt*16+lr];
    // deferred softmax division applied here (z*rs)
#pragma unroll
    for (int ct = 0; ct < 2; ++ct) {
      f32x4 z = {0.f, 0.f, 0.f, 0.f};
#pragma unroll
      for (int kc = 0; kc < 2; ++kc) mfma16(z, bv[ct][kc], ap[kc]);
      uint2 oo = { pkh(z[0] * rs, z[1] * rs), pkh(z[2] * rs, z[3] * rs) };
      int row = nt * 16 + lr;
      int colb = h32 * 2 + ct * 32 + lg * 8;   // 4 consecutive channels, 8B
      *(uint2*)(smem + RX2 + row * 256 + swz(row, colb)) = oo;
    }
  }

  // hoist proj weight frags (L2) to overlap with the barrier
  u32x4 bp[2][4];
#pragma unroll
  for (int ct = 0; ct < 2; ++ct)
#pragma unroll
    for (int kc = 0; kc < 4; ++kc)
      bp[ct][kc] = gfrag(pw_ + (h32 + ct * 16 + lr) * 128 + kc * 32 + lg * 8);
  float pbv[2] = { pb[h32 + lr], pb[h32 + 16 + lr] };

  __syncthreads();  // (3) O complete

  // ---- proj (column-scheme): out[:, h32..h32+32) = O @ pw[own rows]^T + pb ----
  {
    float* ob = out + (size_t)b * 8192;
#pragma unroll
    for (int np = 0; np < 2; ++np) {
      u32x4 af[2][4];
#pragma unroll
      for (int t = 0; t < 2; ++t)
#pragma unroll
        for (int kc = 0; kc < 4; ++kc)
          af[t][kc] = ldsfrag(smem + RX2, (np * 2 + t) * 16 + lr, kc * 64 + lg * 16, 256);
#pragma unroll
      for (int t = 0; t < 2; ++t)
#pragma unroll
        for (int ct = 0; ct < 2; ++ct) {
          f32x4 acc = {0.f, 0.f, 0.f, 0.f};
#pragma unroll
          for (int kc = 0; kc < 4; ++kc) mfma16(acc, af[t][kc], bp[ct][kc]);
#pragma unroll
          for (int i = 0; i < 4; ++i) {
            int row = (np * 2 + t) * 16 + lg * 4 + i;
            ob[row * 128 + h32 + ct * 16 + lr] = acc[i] + pbv[ct];
          }
        }
    }
  }
}

extern "C" void kernel_launch(void* const* d_in, const int* in_sizes, int n_in,
                              void* d_out, int out_size, void* d_ws, size_t ws_size,
                              hipStream_t stream) {
  const float* x1 = (const float*)d_in[0];
  const float* x2 = (const float*)d_in[1];
  const float* qw = (const float*)d_in[2];
  const float* qb = (const float*)d_in[3];
  const float* kvw = (const float*)d_in[4];
  const float* vb = (const float*)d_in[5];
  const float* ls = (const float*)d_in[6];
  const float* pw = (const float*)d_in[7];
  const float* pb = (const float*)d_in[8];
  u16* wh = (u16*)d_ws;                           // 65536 f16 = 128 KB
  float* scales = (float*)((char*)d_ws + 131072); // 4 floats

  wca_prep<<<64, 256, 0, stream>>>(qw, kvw, pw, ls, wh, scales);
  wca_kernel<<<NWIN, 256, 0, stream>>>(x1, x2, qb, vb, pb, wh, scales, (float*)d_out);
}

// Round 23
// 227.170 us; speedup vs baseline: 1.2977x; 1.2977x over previous
//
#include <hip/hip_runtime.h>

typedef float f32x4 __attribute__((ext_vector_type(4)));
typedef unsigned int u32x4 __attribute__((ext_vector_type(4)));
typedef _Float16 f16x8 __attribute__((ext_vector_type(8)));
typedef unsigned short u16;
typedef unsigned int u32;

// ---- constants ----
#define NWIN 8192
#define MAX_LOG_SCALE 4.605170185988091f  // log(100)
#define LOG2E 1.4426950408889634f

// Wave = head end-to-end; 3 barriers; launch_bounds(256,4) (occupancy doubly
// pinned: LDS 40KB -> 4 blocks/CU and regs -> 4 waves/EU; (256,5+) useless).
// Round 23 = R22 + kc-OUTER Q-projection: all 4 nt q-tiles accumulated with
// each qw fragment loaded ONCE (8 frags vs 32/wave). Rationale: 3 flat rounds
// with VALU 46->28% prove latency-bound; L2 traffic ~17 TB/s (~48% ceiling)
// and per-nt qw frag loads feed MFMAs directly = exposed L2 latency 4x/wave.
// R18's hoist proved the mechanism (+18us gross despite spill); this form
// holds +32 AGPR accumulators instead of +32 VGPR weights (transient frags,
// 2 live at a time) -> no spill expected.
// PLATFORM RULE (R15/R16): __shfl_* across the 32-lane boundary is broken —
// masks 1/2/4/8 only; cross-group sums go through pex (LDS, in-order).
// LDS (40 KB -> 4 blocks/CU):
//   RX1  [0,16K):   x1 f16 [64][128] swz
//   RX2  [16K,32K): x2 f16 [64][128] swz -> O overlay after barrier (2)
//   RBNC [32K,40K): per-wave 2 KB strip (vT s128swz -> k-hat s80 -> q-raw s80
//                   -> P s128swz, sequential wave-local; pex@1792)
#define RX1 0
#define RX2 16384
#define RBNC 32768
#define LDS_BYTES 40960

__device__ __forceinline__ void mfma16(f32x4& acc, u32x4 a, u32x4 b) {
  acc = __builtin_amdgcn_mfma_f32_16x16x32_f16(
      __builtin_bit_cast(f16x8, a), __builtin_bit_cast(f16x8, b), acc, 0, 0, 0);
}

__device__ __forceinline__ u16 f2h(float f) {
  return __builtin_bit_cast(u16, (_Float16)f);
}
__device__ __forceinline__ u32 pkh(float x, float y) {  // packed f32->f16 (RTZ)
  return __builtin_bit_cast(u32, __builtin_amdgcn_cvt_pkrtz(x, y));
}

// XOR swizzle within a row (row stride 256B or 128B); bijective, stays in-row.
__device__ __forceinline__ int swz(int row, int colbyte) {
  return colbyte ^ ((row & 7) << 4);
}
__device__ __forceinline__ u32x4 ldsfrag(const char* p, int row, int colbyte, int stride) {
  return *(const u32x4*)(p + row * stride + swz(row, colbyte));
}
__device__ __forceinline__ void lds_st16(char* p, int row, int colbyte, int stride, u16 v) {
  *(u16*)(p + row * stride + swz(row, colbyte)) = v;
}
__device__ __forceinline__ u32x4 gfrag(const u16* p) {
  return *(const u32x4*)p;
}

// ---------- weight prep: f32 -> f16 (contiguous qw|kvw|pw) + head scales ----------
__global__ void wca_prep(const float* __restrict__ qw, const float* __restrict__ kvw,
                         const float* __restrict__ pw, const float* __restrict__ ls,
                         u16* __restrict__ wh, float* __restrict__ scales) {
  int t = blockIdx.x * 256 + threadIdx.x;   // 0..16383, one float4 each
  int e = t * 4;
  const float* src;
  int off;
  if (e < 16384)      { src = qw;  off = e; }
  else if (e < 49152) { src = kvw; off = e - 16384; }
  else                { src = pw;  off = e - 49152; }
  float4 v = *(const float4*)(src + off);
  uint2 o = { pkh(v.x, v.y), pkh(v.z, v.w) };
  *(uint2*)(wh + e) = o;
  if (t < 4) scales[t] = __expf(fminf(ls[t], MAX_LOG_SCALE)) * LOG2E;
}

// ---------- main kernel: one window per block, wave = head, 3 barriers ----------
__global__ void __launch_bounds__(256, 4) wca_kernel(
    const float* __restrict__ x1, const float* __restrict__ x2,
    const float* __restrict__ qb, const float* __restrict__ vb,
    const float* __restrict__ pb, const u16* __restrict__ wh,
    const float* __restrict__ scales, float* __restrict__ out) {
  __shared__ char smem[LDS_BYTES];
  const int b = blockIdx.x;
  const int tid = threadIdx.x;
  const int wv = tid >> 6;          // wave = head 0..3
  const int lane = tid & 63;
  const int lr = lane & 15;
  const int lg = lane >> 4;
  const int h32 = wv * 32;
  const u16* qw_  = wh;                     // 128x128
  const u16* kvwk = wh + 16384;             // k-part rows 0..127
  const u16* kvwv = wh + 16384 + 16384;     // v-part rows 0..127
  const u16* pw_  = wh + 49152;             // 128x128
  char* bnc = smem + RBNC + wv * 2048;      // wave-private bounce strip
  char* pex = bnc + 1792;                   // 256B partial-sum exchange area

  // ---- phase 0: stage x1 AND x2 -> f16 LDS (all 16 loads hoisted) ----
  {
    const float4* p1 = (const float4*)(x1 + (size_t)b * 8192);
    const float4* p2 = (const float4*)(x2 + (size_t)b * 8192);
    float4 a[8], c[8];
#pragma unroll
    for (int i = 0; i < 8; ++i) { a[i] = p1[i * 256 + tid]; c[i] = p2[i * 256 + tid]; }
#pragma unroll
    for (int i = 0; i < 8; ++i) {
      int e = (i * 256 + tid) * 4;
      int row = e >> 7;
      int colb = (e & 127) * 2;
      uint2 pa = { pkh(a[i].x, a[i].y), pkh(a[i].z, a[i].w) };
      uint2 pc = { pkh(c[i].x, c[i].y), pkh(c[i].z, c[i].w) };
      *(uint2*)(smem + RX1 + row * 256 + swz(row, colb)) = pa;
      *(uint2*)(smem + RX2 + row * 256 + swz(row, colb)) = pc;
    }
  }
  __syncthreads();  // (1) x1,x2 visible

  // ---- V pass: vT(c,m) = sum_k kvw_v[h32+c][k]*x2[m][k] + vb (jt-merged) ----
  u32x4 bv[2][2];
  {
    u32x4 akv[2][4];
#pragma unroll
    for (int jt = 0; jt < 2; ++jt)
#pragma unroll
      for (int kc = 0; kc < 4; ++kc)
        akv[jt][kc] = gfrag(kvwv + (h32 + jt * 16 + lr) * 128 + kc * 32 + lg * 8);
    f32x4 vc[2][4];
#pragma unroll
    for (int jt = 0; jt < 2; ++jt)
#pragma unroll
      for (int nt = 0; nt < 4; ++nt) vc[jt][nt] = (f32x4){0.f, 0.f, 0.f, 0.f};
#pragma unroll
    for (int nt = 0; nt < 4; ++nt) {
      u32x4 bx[4];
#pragma unroll
      for (int kc = 0; kc < 4; ++kc)
        bx[kc] = ldsfrag(smem + RX2, nt * 16 + lr, kc * 64 + lg * 16, 256);
#pragma unroll
      for (int jt = 0; jt < 2; ++jt)
#pragma unroll
        for (int kc = 0; kc < 4; ++kc) mfma16(vc[jt][nt], akv[jt][kc], bx[kc]);
    }
#pragma unroll
    for (int jt = 0; jt < 2; ++jt) {
      float vbias[4];
#pragma unroll
      for (int i = 0; i < 4; ++i) vbias[i] = vb[h32 + jt * 16 + lg * 4 + i];
#pragma unroll
      for (int nt = 0; nt < 4; ++nt)
#pragma unroll
        for (int i = 0; i < 4; ++i)
          lds_st16(bnc, lg * 4 + i, (nt * 16 + lr) * 2, 128,
                   f2h(vc[jt][nt][i] + vbias[i]));
#pragma unroll
      for (int kc = 0; kc < 2; ++kc)
        bv[jt][kc] = ldsfrag(bnc, lr, kc * 64 + lg * 16, 128);  // wave-local RAW
    }
  }

  // ---- K pass (SWAPPED): lane holds k[tok=mt*16+lr][ch lg*4+i | 16+lg*4+i] ----
  u32x4 bk[4];
  {
    u32x4 bkw[2][4];
#pragma unroll
    for (int jt = 0; jt < 2; ++jt)
#pragma unroll
      for (int kc = 0; kc < 4; ++kc)
        bkw[jt][kc] = gfrag(kvwk + (h32 + jt * 16 + lr) * 128 + kc * 32 + lg * 8);
#pragma unroll
    for (int mt = 0; mt < 4; ++mt) {
      f32x4 c0 = {0.f, 0.f, 0.f, 0.f}, c1 = {0.f, 0.f, 0.f, 0.f};
#pragma unroll
      for (int kc = 0; kc < 4; ++kc) {
        u32x4 ax = ldsfrag(smem + RX2, mt * 16 + lr, kc * 64 + lg * 16, 256);
        mfma16(c0, bkw[0][kc], ax);   // A=weights(channels), B=x2(tokens)
        mfma16(c1, bkw[1][kc], ax);
      }
      // lane-local channel sum + pex exchange across lg groups (no 16/32 shfl)
      float ss = 0.f;
#pragma unroll
      for (int i = 0; i < 4; ++i)
        ss = fmaf(c0[i], c0[i], fmaf(c1[i], c1[i], ss));
      *(float*)(pex + lr * 16 + lg * 4) = ss;
      float4 ps = *(const float4*)(pex + lr * 16);
      float rn = 1.0f / fmaxf(sqrtf(ps.x + ps.y + ps.z + ps.w), 1e-12f);
      // packed k-hat store: [tok=lr][ch] stride 80 (proven bank pattern)
      uint2 k0 = { pkh(c0[0] * rn, c0[1] * rn), pkh(c0[2] * rn, c0[3] * rn) };
      uint2 k1 = { pkh(c1[0] * rn, c1[1] * rn), pkh(c1[2] * rn, c1[3] * rn) };
      *(uint2*)(bnc + lr * 80 + lg * 8) = k0;
      *(uint2*)(bnc + lr * 80 + 32 + lg * 8) = k1;
      bk[mt] = *(const u32x4*)(bnc + lr * 80 + lg * 16);  // wave-local RAW
    }
  }
  __syncthreads();  // (2) all waves done reading x2 -> O may overlay RX2

  // ---- Q projection, kc-OUTER: each qw frag loaded ONCE (8 total) ----
  const float sc = scales[wv];  // includes log2(e)
  f32x4 q0a[4], q1a[4];         // raw q accumulators for all 4 nt tiles
#pragma unroll
  for (int nt = 0; nt < 4; ++nt) {
    q0a[nt] = (f32x4){0.f, 0.f, 0.f, 0.f};
    q1a[nt] = (f32x4){0.f, 0.f, 0.f, 0.f};
  }
#pragma unroll
  for (int kc = 0; kc < 4; ++kc) {
    u32x4 w0 = gfrag(qw_ + (h32 + lr) * 128 + kc * 32 + lg * 8);
    u32x4 w1 = gfrag(qw_ + (h32 + 16 + lr) * 128 + kc * 32 + lg * 8);
#pragma unroll
    for (int nt = 0; nt < 4; ++nt) {
      u32x4 a = ldsfrag(smem + RX1, nt * 16 + lr, kc * 64 + lg * 16, 256);
      mfma16(q0a[nt], w0, a);   // SWAPPED: lane holds q[tok=nt*16+lr][ch lg*4+i]
      mfma16(q1a[nt], w1, a);   // channels 16+lg*4+i
    }
  }
  {
    float qb0v[4], qb1v[4];     // bias by CHANNEL (lg*4+i) for swapped layout
#pragma unroll
    for (int i = 0; i < 4; ++i) {
      qb0v[i] = qb[h32 + lg * 4 + i];
      qb1v[i] = qb[h32 + 16 + lg * 4 + i];
    }
#pragma unroll
    for (int nt = 0; nt < 4; ++nt)
#pragma unroll
      for (int i = 0; i < 4; ++i) {
        q0a[nt][i] += qb0v[i];
        q1a[nt][i] += qb1v[i];
      }
  }

  // ---- attention per nt (deferred q-norm, deferred softmax div) ----
#pragma unroll
  for (int nt = 0; nt < 4; ++nt) {
    // store RAW biased q immediately (deferred norm — proven pattern)
    uint2 g0 = { pkh(q0a[nt][0], q0a[nt][1]), pkh(q0a[nt][2], q0a[nt][3]) };
    uint2 g1 = { pkh(q1a[nt][0], q1a[nt][1]), pkh(q1a[nt][2], q1a[nt][3]) };
    *(uint2*)(bnc + lr * 80 + lg * 8) = g0;
    *(uint2*)(bnc + lr * 80 + 32 + lg * 8) = g1;
    // ss + pex overlap the q store->read round trip
    float ss = 0.f;
#pragma unroll
    for (int i = 0; i < 4; ++i)
      ss = fmaf(q0a[nt][i], q0a[nt][i], fmaf(q1a[nt][i], q1a[nt][i], ss));
    *(float*)(pex + lr * 16 + lg * 4) = ss;
    float4 ps0 = *(const float4*)(pex + lr * 16);
    u32x4 aq = *(const u32x4*)(bnc + lr * 80 + lg * 16);  // raw q, token=lr

    // QK (swapped): p4[mt][i] = rawdot[k = mt*16+lg*4+i][q = lr]
    f32x4 p4[4];
#pragma unroll
    for (int mt = 0; mt < 4; ++mt) {
      f32x4 z = {0.f, 0.f, 0.f, 0.f};
      mfma16(z, bk[mt], aq);
      p4[mt] = z;
    }
    // norm folded into exp arg: esc = sc / ||q||  (k already normalized)
    float esc = sc / fmaxf(sqrtf(ps0.x + ps0.y + ps0.z + ps0.w), 1e-12f);
    float psum = 0.f;
#pragma unroll
    for (int mt = 0; mt < 4; ++mt)
#pragma unroll
      for (int i = 0; i < 4; ++i) {
        float p = exp2f(fmaf(p4[mt][i], esc, -sc));
        p4[mt][i] = p;
        psum += p;
      }
    // pex(psum) write + READ precede the P store (pex aliases P rows 14-15);
    // rs is computed late so the P->ap->PV chain never waits on it.
    *(float*)(pex + lr * 16 + lg * 4) = psum;
    float4 ps1 = *(const float4*)(pex + lr * 16);

    // P store UNNORMALIZED -> strip [row=q=lr][col=m], stride 128 swz, 8B packed
#pragma unroll
    for (int mt = 0; mt < 4; ++mt) {
      uint2 pp = { pkh(p4[mt][0], p4[mt][1]), pkh(p4[mt][2], p4[mt][3]) };
      int colb = mt * 32 + lg * 8;
      *(uint2*)(bnc + lr * 128 + swz(lr, colb)) = pp;
    }
    // ap read (row = lr, m = kc*32 + lg*8 + j)
    u32x4 ap[2];
#pragma unroll
    for (int kc = 0; kc < 2; ++kc)
      ap[kc] = ldsfrag(bnc, lr, kc * 64 + lg * 16, 128);  // wave-local RAW
    const float rs = 1.0f / (ps1.x + ps1.y + ps1.z + ps1.w);  // late use of ps1

    // PV SWAPPED: lane holds O[ch = h32+ct*16+lg*4+i][tok = nt*16+lr];
    // deferred softmax division applied here (z*rs)
#pragma unroll
    for (int ct = 0; ct < 2; ++ct) {
      f32x4 z = {0.f, 0.f, 0.f, 0.f};
#pragma unroll
      for (int kc = 0; kc < 2; ++kc) mfma16(z, bv[ct][kc], ap[kc]);
      uint2 oo = { pkh(z[0] * rs, z[1] * rs), pkh(z[2] * rs, z[3] * rs) };
      int row = nt * 16 + lr;
      int colb = h32 * 2 + ct * 32 + lg * 8;   // 4 consecutive channels, 8B
      *(uint2*)(smem + RX2 + row * 256 + swz(row, colb)) = oo;
    }
  }

  // hoist proj weight frags (L2) to overlap with the barrier
  u32x4 bp[2][4];
#pragma unroll
  for (int ct = 0; ct < 2; ++ct)
#pragma unroll
    for (int kc = 0; kc < 4; ++kc)
      bp[ct][kc] = gfrag(pw_ + (h32 + ct * 16 + lr) * 128 + kc * 32 + lg * 8);
  float pbv[2] = { pb[h32 + lr], pb[h32 + 16 + lr] };

  __syncthreads();  // (3) O complete

  // ---- proj (column-scheme): out[:, h32..h32+32) = O @ pw[own rows]^T + pb ----
  {
    float* ob = out + (size_t)b * 8192;
#pragma unroll
    for (int np = 0; np < 2; ++np) {
      u32x4 af[2][4];
#pragma unroll
      for (int t = 0; t < 2; ++t)
#pragma unroll
        for (int kc = 0; kc < 4; ++kc)
          af[t][kc] = ldsfrag(smem + RX2, (np * 2 + t) * 16 + lr, kc * 64 + lg * 16, 256);
#pragma unroll
      for (int t = 0; t < 2; ++t)
#pragma unroll
        for (int ct = 0; ct < 2; ++ct) {
          f32x4 acc = {0.f, 0.f, 0.f, 0.f};
#pragma unroll
          for (int kc = 0; kc < 4; ++kc) mfma16(acc, af[t][kc], bp[ct][kc]);
#pragma unroll
          for (int i = 0; i < 4; ++i) {
            int row = (np * 2 + t) * 16 + lg * 4 + i;
            ob[row * 128 + h32 + ct * 16 + lr] = acc[i] + pbv[ct];
          }
        }
    }
  }
}

extern "C" void kernel_launch(void* const* d_in, const int* in_sizes, int n_in,
                              void* d_out, int out_size, void* d_ws, size_t ws_size,
                              hipStream_t stream) {
  const float* x1 = (const float*)d_in[0];
  const float* x2 = (const float*)d_in[1];
  const float* qw = (const float*)d_in[2];
  const float* qb = (const float*)d_in[3];
  const float* kvw = (const float*)d_in[4];
  const float* vb = (const float*)d_in[5];
  const float* ls = (const float*)d_in[6];
  const float* pw = (const float*)d_in[7];
  const float* pb = (const float*)d_in[8];
  u16* wh = (u16*)d_ws;                           // 65536 f16 = 128 KB
  float* scales = (float*)((char*)d_ws + 131072); // 4 floats

  wca_prep<<<64, 256, 0, stream>>>(qw, kvw, pw, ls, wh, scales);
  wca_kernel<<<NWIN, 256, 0, stream>>>(x1, x2, qb, vb, pb, wh, scales, (float*)d_out);
}